// Round 8
// baseline (550.095 us; speedup 1.0000x reference)
//
#include <hip/hip_runtime.h>

#define TSTEPS 1023
#define GAMMA  (0.01f / 32.0f)   // LR * dL/dy scale: 2/(64*2) folded
#define EPSV   1e-5f

// workspace layout (float offsets)
#define WS_HS 0       // 64*64 hs table
#define WS_G  4096    // 64*64 PRE-SCALED gram: Gs = GAMMA*G + GAMMA
#define WS_Z0 8192    // 64*16 initial Ztilde = hs@w1 + b1

typedef float v4f __attribute__((ext_vector_type(4)));
typedef unsigned int v2u __attribute__((ext_vector_type(2)));

template<int CTRL>
__device__ __forceinline__ float dppmov(float x) {
    return __int_as_float(__builtin_amdgcn_update_dpp(0, __float_as_int(x), CTRL, 0xF, 0xF, true));
}
__device__ __forceinline__ v2u swap16(float a, float b) {
    return __builtin_amdgcn_permlane16_swap(__float_as_uint(a), __float_as_uint(b), false, false);
}
__device__ __forceinline__ v2u swap32(float a, float b) {
    return __builtin_amdgcn_permlane32_swap(__float_as_uint(a), __float_as_uint(b), false, false);
}
__device__ __forceinline__ float rlane(float v, int sl) {
    return __int_as_float(__builtin_amdgcn_readlane(__float_as_int(v), sl));
}
#define U2F(x) __uint_as_float(x)

// sum over lane bits 0,1 (j-quad fold), result replicated across the quad
__device__ __forceinline__ float qfold(float x) {
    x += dppmov<0xB1>(x);    // quad_perm xor1
    x += dppmov<0x4E>(x);    // quad_perm xor2
    return x;
}
// sum over lane bits 2..5 (h_local fold), jg preserved, replicated
__device__ __forceinline__ float hfold(float x) {
    x += dppmov<0x124>(x);               // row_ror:4  (lane bit2)
    x += dppmov<0x128>(x);               // row_ror:8  (lane bit3)
    v2u a = swap16(x, x);                // lane bit4: pair values
    x = U2F(a[0]) + U2F(a[1]);
    v2u b = swap32(x, x);                // lane bit5
    x = U2F(b[0]) + U2F(b[1]);
    return x;
}

// ---------------- kernel A: hs table (per-token embed->FFN->LN), 64 blocks ----------------
__global__ void hs_kernel(const float* __restrict__ embed,
                          const float* __restrict__ ffw1, const float* __restrict__ ffb1,
                          const float* __restrict__ ffw2, const float* __restrict__ ffb2,
                          const float* __restrict__ lng,  const float* __restrict__ lnb,
                          float* __restrict__ ws) {
    __shared__ float e[64];
    __shared__ float a1[128];
    int w = blockIdx.x;
    int tid = threadIdx.x;
    if (tid < 64) e[tid] = embed[w * 64 + tid];
    __syncthreads();
    float z1 = ffb1[tid];
    for (int x = 0; x < 64; ++x) z1 += e[x] * ffw1[x * 128 + tid];
    a1[tid] = fmaxf(z1, 0.0f);
    __syncthreads();
    if (tid < 64) {
        float f = ffb2[tid];
        for (int i = 0; i < 128; ++i) f += a1[i] * ffw2[i * 64 + tid];
        float hv = e[tid] + f;
        float s = hv;
#pragma unroll
        for (int m = 32; m >= 1; m >>= 1) s += __shfl_xor(s, m);
        float mu = s * (1.0f / 64.0f);
        float dv = hv - mu;
        float vs = dv * dv;
#pragma unroll
        for (int m = 32; m >= 1; m >>= 1) vs += __shfl_xor(vs, m);
        float rstd = 1.0f / sqrtf(vs * (1.0f / 64.0f) + EPSV);
        ws[WS_HS + w * 64 + tid] = dv * rstd * lng[tid] + lnb[tid];
    }
}

// ---------------- kernel B: pre-scaled Gram + Ztilde0, 64 blocks ----------------
__global__ void gz_kernel(const float* __restrict__ w1, const float* __restrict__ b1,
                          float* __restrict__ ws) {
    __shared__ float row[64];
    int w = blockIdx.x, tid = threadIdx.x;
    row[tid] = ws[WS_HS + w * 64 + tid];
    __syncthreads();
    float g = 0.0f;
    for (int x = 0; x < 64; ++x) g += row[x] * ws[WS_HS + tid * 64 + x];
    ws[WS_G + w * 64 + tid] = GAMMA * g + GAMMA;      // pre-scaled
    if (tid < 16) {
        float z = b1[tid];
        for (int x = 0; x < 64; ++x) z += row[x] * w1[x * 16 + tid];
        ws[WS_Z0 + w * 16 + tid] = z;
    }
}

// ---------------- main kernel: 4-wave H-SPLIT TTT scan ----------------
// Wave wv owns output dims h in [16wv,16wv+16). Lane = (hl=lane>>2, jg=lane&3);
// h = 16wv+hl. Per lane: W2c = W2[4jg..4jg+4)[h], z2c = z2[4jg..) (replicated
// over hl), ybias = b2[h], vv = hs[v][h]. d_h is WAVE-LOCAL: y-partial (4 fma)
// + qfold over jg -> no y exchange. The exchange carries the already-reduced
// dz-partials: dzp_w[j] = sum_{h in slice} mask_j W2[j,h] d_h (4 muls + hfold,
// all PRE-barrier). Post-barrier: 4 b128 broadcast reads + fixed tree ->
// dz[j] -> z2 = E - cz*dz -> next forward. Chain ~230cy vs R3's ~310.
// Z register-resident as R3: lane = row, storage quad = wv; E published
// pre-barrier via readlane (Zv through t-1; cz*dz lag-correction identical to
// R3). dz for the storage quad via uniform-address broadcast reads. All sums
// fixed trees -> deterministic. Update equations byte-identical to R3's.
struct TTTHSmem {
    float hs[4096];
    float Gs[4096];
    int   sq[2048];                 // unguarded prefetch reads sq[2048..2049] -> land in dzpub[0][0][0..1] (harmless)
    float dzpub[2][4][16];          // [parity][wave][j] dz-partials
    float epub[2][4][4];            // [parity][j-quad][i] E row publish
    float ctxp[64];                 // final ctx (fully summed)
};

__launch_bounds__(256, 1)
__global__ void ttt_kernel(const int* __restrict__ seq,
                           const float* __restrict__ w2, const float* __restrict__ b2i,
                           const float* __restrict__ outw, const float* __restrict__ outb,
                           const float* __restrict__ ws, float* __restrict__ out) {
    __shared__ TTTHSmem sm;

    const int b    = blockIdx.x;
    const int tid  = threadIdx.x;
    const int wv   = tid >> 6;
    const int lane = tid & 63;
    const int jg   = lane & 3;          // compute j-quad
    const int hl   = lane >> 2;         // h within wave's slice
    const int h    = 16 * wv + hl;      // owned output dim

    {   // vectorized staging (256 threads)
        float4*       hv = (float4*)sm.hs;
        const float4* sv = (const float4*)(ws + WS_HS);
#pragma unroll
        for (int m = 0; m < 4; ++m) hv[m * 256 + tid] = sv[m * 256 + tid];
        float4*       gv = (float4*)sm.Gs;
        const float4* gs = (const float4*)(ws + WS_G);
#pragma unroll
        for (int m = 0; m < 4; ++m) gv[m * 256 + tid] = gs[m * 256 + tid];
        int4*       qv = (int4*)sm.sq;
        const int4* qs = (const int4*)(seq + b * 2048);
#pragma unroll
        for (int m = 0; m < 2; ++m) qv[m * 256 + tid] = qs[m * 256 + tid];
    }

    // W2 compute slice: W2[4jg+i][h]
    v4f W2c;
    W2c.x = w2[(4 * jg + 0) * 64 + h];
    W2c.y = w2[(4 * jg + 1) * 64 + h];
    W2c.z = w2[(4 * jg + 2) * 64 + h];
    W2c.w = w2[(4 * jg + 3) * 64 + h];
    float ybias = b2i[h];               // full b2 per owned h (no cross-wave y-sum)

    // Z storage: lane = row, this wave's storage quad [4wv..4wv+4), registers
    v4f Zv = *(const v4f*)(ws + WS_Z0 + lane * 16 + 4 * wv);
    __syncthreads();

    int tk = sm.sq[0];
    // z2 of first key token, compute quad (replicated across hl by construction)
    v4f z2c = *(const v4f*)(ws + WS_Z0 + tk * 16 + 4 * jg);
    float vv = sm.hs[sm.sq[1] * 64 + h];
    float cr = sm.Gs[tk * 64 + lane];   // pre-scaled gamma*(G+1), row tk (lane=row)

    int2 pairT  = *(const int2*)(sm.sq + 2);
    int2 pairT1 = *(const int2*)(sm.sq + 4);

    const v4f zero4 = {0.0f, 0.0f, 0.0f, 0.0f};

    // main loop: steps 0..1021 (last step peeled)
#pragma unroll 2
    for (int t = 0; t < TSTEPS - 1; ++t) {
        const int tkn = pairT.x;
        const int tvn = pairT.y;
        const int par = t & 1;
        const int stkn = __builtin_amdgcn_readfirstlane(tkn);

        // ---- forward: d is wave-local ----
        const v4f a = __builtin_elementwise_max(z2c, zero4);
        const float yp = a.x * W2c.x + a.y * W2c.y + a.z * W2c.z + a.w * W2c.w;
        const float yf = qfold(yp);
        const float d  = (ybias + yf) - vv;

        // ---- dz partials: masked products (pre-update W2) + h-fold ----
        const v4f pr = W2c * d;
        float p0 = (a.x > 0.0f) ? pr.x : 0.0f;
        float p1 = (a.y > 0.0f) ? pr.y : 0.0f;
        float p2 = (a.z > 0.0f) ? pr.z : 0.0f;
        float p3 = (a.w > 0.0f) ? pr.w : 0.0f;
        p0 = hfold(p0); p1 = hfold(p1); p2 = hfold(p2); p3 = hfold(p3);

        // ---- local updates (pre-barrier; dzp already consumed pre-update W2) ----
        const float sd = GAMMA * d;
        ybias -= sd;
        W2c = W2c - sd * a;

        // ---- E of next key row (Zv through t-1) + cz, via readlane ----
        const float E0 = rlane(Zv.x, stkn);
        const float E1 = rlane(Zv.y, stkn);
        const float E2 = rlane(Zv.z, stkn);
        const float E3 = rlane(Zv.w, stkn);
        const float cz = rlane(cr, stkn);        // Gs[tk*64 + tkn]

        // ---- publishes ----
        if (lane < 4)  *(v4f*)&sm.dzpub[par][wv][4 * lane] = v4f{p0, p1, p2, p3};
        if (lane == 0) *(v4f*)&sm.epub[par][wv][0] = v4f{E0, E1, E2, E3};
        __syncthreads();

        // ---- reads: compute-quad dz partials (16-way broadcast, conflict-free) ----
        const v4f A  = *(const v4f*)&sm.dzpub[par][0][4 * jg];
        const v4f B  = *(const v4f*)&sm.dzpub[par][1][4 * jg];
        const v4f C  = *(const v4f*)&sm.dzpub[par][2][4 * jg];
        const v4f D  = *(const v4f*)&sm.dzpub[par][3][4 * jg];
        const v4f Eq = *(const v4f*)&sm.epub[par][jg][0];
        // storage-quad dz partials (uniform address -> broadcast)
        const v4f As = *(const v4f*)&sm.dzpub[par][0][4 * wv];
        const v4f Bs = *(const v4f*)&sm.dzpub[par][1][4 * wv];
        const v4f Cs = *(const v4f*)&sm.dzpub[par][2][4 * wv];
        const v4f Ds = *(const v4f*)&sm.dzpub[par][3][4 * wv];
        // next-step prefetches
        const float vnext = sm.hs[tvn * 64 + h];
        const float crn   = sm.Gs[tkn * 64 + lane];
        const int2 pairT2 = *(const int2*)(sm.sq + 2 * t + 6);  // t=1021 overrun: discarded

        // ---- dz (fixed trees, identical in all consumers) ----
        const v4f dz4 = (A + B) + (C + D);       // compute quad
        z2c = Eq - cz * dz4;                     // lag-corrected next-key state
        const v4f dzS = (As + Bs) + (Cs + Ds);   // storage quad
        Zv = Zv - cr * dzS;                      // prompt register-Z update

        vv = vnext;
        cr = crn;
        pairT = pairT1;
        pairT1 = pairT2;
    }

    // ---- peeled final step (t = 1022, par = 0): tkn = query token sq[2047] ----
    {
        const int tkn = pairT.y;                 // pairT = {sq[2046], sq[2047]}
        const int stkn = __builtin_amdgcn_readfirstlane(tkn);

        const v4f a = __builtin_elementwise_max(z2c, zero4);
        const float yp = a.x * W2c.x + a.y * W2c.y + a.z * W2c.z + a.w * W2c.w;
        const float yf = qfold(yp);
        const float d  = (ybias + yf) - vv;

        const v4f pr = W2c * d;
        float p0 = (a.x > 0.0f) ? pr.x : 0.0f;
        float p1 = (a.y > 0.0f) ? pr.y : 0.0f;
        float p2 = (a.z > 0.0f) ? pr.z : 0.0f;
        float p3 = (a.w > 0.0f) ? pr.w : 0.0f;
        p0 = hfold(p0); p1 = hfold(p1); p2 = hfold(p2); p3 = hfold(p3);

        const float sd = GAMMA * d;
        ybias -= sd;
        W2c = W2c - sd * a;

        const float E0 = rlane(Zv.x, stkn);      // Zv through step 1021
        const float E1 = rlane(Zv.y, stkn);
        const float E2 = rlane(Zv.z, stkn);
        const float E3 = rlane(Zv.w, stkn);
        const float cz = rlane(cr, stkn);

        if (lane < 4)  *(v4f*)&sm.dzpub[0][wv][4 * lane] = v4f{p0, p1, p2, p3};
        if (lane == 0) *(v4f*)&sm.epub[0][wv][0] = v4f{E0, E1, E2, E3};
        __syncthreads();

        const v4f A  = *(const v4f*)&sm.dzpub[0][0][4 * jg];
        const v4f B  = *(const v4f*)&sm.dzpub[0][1][4 * jg];
        const v4f C  = *(const v4f*)&sm.dzpub[0][2][4 * jg];
        const v4f D  = *(const v4f*)&sm.dzpub[0][3][4 * jg];
        const v4f Eq = *(const v4f*)&sm.epub[0][jg][0];

        const v4f dz4 = (A + B) + (C + D);
        z2c = Eq - cz * dz4;                     // query-token state
    }

    // ---- final eval: ctx_h = b2_f + sum_j relu(z_q)[j] W2_f[j,h] ----
    {
        const v4f aq = __builtin_elementwise_max(z2c, zero4);
        const float cp = aq.x * W2c.x + aq.y * W2c.y + aq.z * W2c.z + aq.w * W2c.w;
        const float ctx = ybias + qfold(cp);
        if (jg == 0) sm.ctxp[h] = ctx;           // replicated across jg; one writer
    }
    __syncthreads();
    if (wv == 0) {
        float o = outb[lane];
        for (int hh = 0; hh < 64; ++hh)
            o += sm.ctxp[hh] * outw[hh * 64 + lane];
        out[b * 64 + lane] = o;
    }
}

// ---------------- launcher ----------------
extern "C" void kernel_launch(void* const* d_in, const int* in_sizes, int n_in,
                              void* d_out, int out_size, void* d_ws, size_t ws_size,
                              hipStream_t stream) {
    const int*   seq   = (const int*)d_in[0];
    const float* embed = (const float*)d_in[1];
    const float* ffw1  = (const float*)d_in[2];
    const float* ffb1  = (const float*)d_in[3];
    const float* ffw2  = (const float*)d_in[4];
    const float* ffb2  = (const float*)d_in[5];
    const float* lng   = (const float*)d_in[6];
    const float* lnb   = (const float*)d_in[7];
    const float* w1    = (const float*)d_in[8];
    const float* b1    = (const float*)d_in[9];
    const float* w2    = (const float*)d_in[10];
    const float* b2    = (const float*)d_in[11];
    const float* outw  = (const float*)d_in[12];
    const float* outb  = (const float*)d_in[13];
    float* ws  = (float*)d_ws;
    float* out = (float*)d_out;

    hipLaunchKernelGGL(hs_kernel, dim3(64), dim3(128), 0, stream,
                       embed, ffw1, ffb1, ffw2, ffb2, lng, lnb, ws);
    hipLaunchKernelGGL(gz_kernel, dim3(64), dim3(64), 0, stream, w1, b1, ws);
    hipLaunchKernelGGL(ttt_kernel, dim3(256), dim3(256), 0, stream,
                       seq, w2, b2, outw, outb, ws, out);
}

// Round 9
// 359.754 us; speedup vs baseline: 1.5291x; 1.5291x over previous
//
#include <hip/hip_runtime.h>

#define TSTEPS 1023
#define GAMMA  (0.01f / 32.0f)   // LR * dL/dy scale: 2/(64*2) folded
#define EPSV   1e-5f

// workspace layout (float offsets)
#define WS_HS 0       // 64*64 hs table
#define WS_G  4096    // 64*64 PRE-SCALED gram: Gs = GAMMA*G + GAMMA
#define WS_Z0 8192    // 64*16 initial Ztilde = hs@w1 + b1

typedef float v2f __attribute__((ext_vector_type(2)));
typedef unsigned int v2u __attribute__((ext_vector_type(2)));

template<int CTRL>
__device__ __forceinline__ float dppmov(float x) {
    return __int_as_float(__builtin_amdgcn_update_dpp(0, __float_as_int(x), CTRL, 0xF, 0xF, true));
}
__device__ __forceinline__ v2u swap16(float a, float b) {
    return __builtin_amdgcn_permlane16_swap(__float_as_uint(a), __float_as_uint(b), false, false);
}
__device__ __forceinline__ v2u swap32(float a, float b) {
    return __builtin_amdgcn_permlane32_swap(__float_as_uint(a), __float_as_uint(b), false, false);
}
__device__ __forceinline__ float rlane(float v, int sl) {
    return __int_as_float(__builtin_amdgcn_readlane(__float_as_int(v), sl));
}
#define U2F(x) __uint_as_float(x)

// ---------------- kernel A: hs table (per-token embed->FFN->LN), 64 blocks ----------------
__global__ void hs_kernel(const float* __restrict__ embed,
                          const float* __restrict__ ffw1, const float* __restrict__ ffb1,
                          const float* __restrict__ ffw2, const float* __restrict__ ffb2,
                          const float* __restrict__ lng,  const float* __restrict__ lnb,
                          float* __restrict__ ws) {
    __shared__ float e[64];
    __shared__ float a1[128];
    int w = blockIdx.x;
    int tid = threadIdx.x;
    if (tid < 64) e[tid] = embed[w * 64 + tid];
    __syncthreads();
    float z1 = ffb1[tid];
    for (int x = 0; x < 64; ++x) z1 += e[x] * ffw1[x * 128 + tid];
    a1[tid] = fmaxf(z1, 0.0f);
    __syncthreads();
    if (tid < 64) {
        float f = ffb2[tid];
        for (int i = 0; i < 128; ++i) f += a1[i] * ffw2[i * 64 + tid];
        float hv = e[tid] + f;
        float s = hv;
#pragma unroll
        for (int m = 32; m >= 1; m >>= 1) s += __shfl_xor(s, m);
        float mu = s * (1.0f / 64.0f);
        float dv = hv - mu;
        float vs = dv * dv;
#pragma unroll
        for (int m = 32; m >= 1; m >>= 1) vs += __shfl_xor(vs, m);
        float rstd = 1.0f / sqrtf(vs * (1.0f / 64.0f) + EPSV);
        ws[WS_HS + w * 64 + tid] = dv * rstd * lng[tid] + lnb[tid];
    }
}

// ---------------- kernel B: pre-scaled Gram + Ztilde0, 64 blocks ----------------
__global__ void gz_kernel(const float* __restrict__ w1, const float* __restrict__ b1,
                          float* __restrict__ ws) {
    __shared__ float row[64];
    int w = blockIdx.x, tid = threadIdx.x;
    row[tid] = ws[WS_HS + w * 64 + tid];
    __syncthreads();
    float g = 0.0f;
    for (int x = 0; x < 64; ++x) g += row[x] * ws[WS_HS + tid * 64 + x];
    ws[WS_G + w * 64 + tid] = GAMMA * g + GAMMA;      // pre-scaled
    if (tid < 16) {
        float z = b1[tid];
        for (int x = 0; x < 64; ++x) z += row[x] * w1[x * 16 + tid];
        ws[WS_Z0 + w * 16 + tid] = z;
    }
}

// ---------------- main kernel: 4-wave j-split, register Z, THINNED LDS TRAFFIC ----------------
// R9 = verified R3 structure + two traffic cuts (the ~300cy gap over the chain
// model is LDS pipe queuing: 32 DS ops/CU/step ~ 185cy shared-pipe occupancy
// that the critical y-reads queue behind):
//  (1) vv folded into wave0's published partial (ypart0 = ybias + acc - vv;
//      d = y0+y1+y2+y3). Waves 1-3 never read hs in the loop: -3 DS/CU/step,
//      d-tree one op shorter. d stays bitwise identical across waves.
//  (2) cr carried one step ahead (crn = Gs[tkn] read post-barrier, consumed
//      next step): cz = rlane(cr, stkn) is register-immediate, cr-read latency
//      fully off-chain. Carried cr at the peeled step = Gs[sq[2044]], exactly
//      R3's explicit read.
// Everything else byte-identical to R3: parity ping-pong ybuf[par][wv][lane]
// (conflict-free b32 broadcasts -- R7 proved the b128 layout's conflicts cost
// more than 4 queued b32s), register-resident Z (row = lane), readlane row
// broadcast, slot permutation X=2*b0, cz*dz one-step lag correction.
struct TTT4Smem {
    float hs[4096];
    float Gs[4096];
    int   sq[2048];                 // unguarded prefetch reads sq[2048..2049] -> land in ybuf (harmless)
    float ybuf[2][4][64];           // [parity][wave][lane] y-partial exchange
    float ctxp[4][64];              // final ctx partials
};

__device__ __forceinline__ void reduce4(const v2f* a2, const v2f* p2, v2f* dz2) {
    // fold lane bit0: partner lane's slot m^2 is the same logical j
    float q0 = p2[0].x + dppmov<0xB1>(p2[1].x);
    float q1 = p2[0].y + dppmov<0xB1>(p2[1].y);
    // relu mask (slot-aligned)
    float rm0 = (a2[0].x > 0.0f) ? q0 : 0.0f;
    float rm1 = (a2[0].y > 0.0f) ? q1 : 0.0f;
    // fold b4 (encodes q-index into b4) then sum over b5
    v2u f01 = swap16(rm0, rm1);
    float T = U2F(f01[0]) + U2F(f01[1]);        // j = b4 + 2*b0, summed over b4-pair
    v2u g01 = swap32(T, T);
    T = U2F(g01[0]) + U2F(g01[1]);              // summed over b5
    // orbit sums over lane bits 1,2,3
    T = T + dppmov<0x122>(T);   // row_ror:2
    T = T + dppmov<0x124>(T);   // row_ror:4
    T = T + dppmov<0x128>(T);   // row_ror:8
    // broadcast: T = dz[b4 + 2*b0] -> all 4 slots (slot m <-> j = m ^ 2*b0)
    v2u u01 = swap16(T, T);
    const float A0 = U2F(u01[0]);               // dz[0 ^ 2b0] -> slot 0
    const float A1 = U2F(u01[1]);               // dz[1 ^ 2b0] -> slot 1
    dz2[0] = {A0, A1};
    dz2[1] = {dppmov<0xB1>(A0), dppmov<0xB1>(A1)};   // slots 2,3 (other b0)
}

__launch_bounds__(256, 1)
__global__ void ttt_kernel(const int* __restrict__ seq,
                           const float* __restrict__ w2, const float* __restrict__ b2i,
                           const float* __restrict__ outw, const float* __restrict__ outb,
                           const float* __restrict__ ws, float* __restrict__ out) {
    __shared__ TTT4Smem sm;

    const int b    = blockIdx.x;
    const int tid  = threadIdx.x;
    const int wv   = tid >> 6;
    const int lane = tid & 63;
    const int b0   = lane & 1;
    const int X    = b0 << 1;              // slot xor: logical j = 4*wv + (slot ^ X)
    const bool pb  = (b0 != 0);
    const bool wv0 = (wv == 0);

    {   // vectorized staging (256 threads)
        float4*       hv = (float4*)sm.hs;
        const float4* sv = (const float4*)(ws + WS_HS);
#pragma unroll
        for (int m = 0; m < 4; ++m) hv[m * 256 + tid] = sv[m * 256 + tid];
        float4*       gv = (float4*)sm.Gs;
        const float4* gs = (const float4*)(ws + WS_G);
#pragma unroll
        for (int m = 0; m < 4; ++m) gv[m * 256 + tid] = gs[m * 256 + tid];
        int4*       qv = (int4*)sm.sq;
        const int4* qs = (const int4*)(seq + b * 2048);
#pragma unroll
        for (int m = 0; m < 2; ++m) qv[m * 256 + tid] = qs[m * 256 + tid];
    }

    // Z state: row = lane, this wave's 4 j-columns, LOGICAL order, registers only
    v2f Zv[2];
    {
        const float4 z0 = *(const float4*)(ws + WS_Z0 + lane * 16 + 4 * wv);
        Zv[0] = {z0.x, z0.y};
        Zv[1] = {z0.z, z0.w};
    }

    // W2 in permuted slot order for this wave's j-slice
    v2f W2p[2];
#pragma unroll
    for (int i = 0; i < 2; ++i) {
        v2f w;
        w.x = w2[(4 * wv + ((2 * i) ^ X)) * 64 + lane];
        w.y = w2[(4 * wv + ((2 * i + 1) ^ X)) * 64 + lane];
        W2p[i] = w;
    }
    float ybias = wv0 ? b2i[lane] : 0.0f;     // b2 lives in wave0's y-partial only
    const float gma = wv0 ? GAMMA : 0.0f;
    __syncthreads();

    // z2 init: row sq[0] broadcast from registers via readlane, permuted slots
    int tk = sm.sq[0];
    v2f z2[2];
    {
        const int stk = __builtin_amdgcn_readfirstlane(tk);
        const float e0 = rlane(Zv[0].x, stk);
        const float e1 = rlane(Zv[0].y, stk);
        const float e2 = rlane(Zv[1].x, stk);
        const float e3 = rlane(Zv[1].y, stk);
        z2[0] = { pb ? e2 : e0, pb ? e3 : e1 };
        z2[1] = { pb ? e0 : e2, pb ? e1 : e3 };
    }
    // vv lives ONLY in wave0 (folded into its y-partial); 0 elsewhere
    float vv = 0.0f;
    if (wv0) vv = sm.hs[sm.sq[1] * 64 + lane];
    // cr carried: row of current key token (pre-scaled gamma*(G+1))
    float cr = sm.Gs[tk * 64 + lane];

    int2 pairT  = *(const int2*)(sm.sq + 2);
    int2 pairT1 = *(const int2*)(sm.sq + 4);

    // main loop: steps 0..1021 (last step peeled)
#pragma unroll 2
    for (int t = 0; t < TSTEPS - 1; ++t) {
        const int tkn = pairT.x;
        const int tvn = pairT.y;
        const int par = t & 1;

        // ---- forward on own j-slice (wave0 folds -vv into its partial) ----
        const v2f zero2 = {0.0f, 0.0f};
        v2f a2[2];
        a2[0] = __builtin_elementwise_max(z2[0], zero2);
        a2[1] = __builtin_elementwise_max(z2[1], zero2);
        v2f accv = a2[0] * W2p[0] + a2[1] * W2p[1];
        const float ypart = ybias + accv.x + accv.y - vv;   // vv == 0 outside wave0

        // ---- y exchange (parity ping-pong, one barrier per step) ----
        sm.ybuf[par][wv][lane] = ypart;
        __syncthreads();   // drain: ypart write is the only outstanding DS write
        // critical reads first
        const float y0 = sm.ybuf[par][0][lane];
        const float y1 = sm.ybuf[par][1][lane];
        const float y2 = sm.ybuf[par][2][lane];
        const float y3 = sm.ybuf[par][3][lane];
        // off-chain prefetches (consumed next step / late this step)
        if (wv0) vv = sm.hs[tvn * 64 + lane];       // next value vector (wave0 only)
        const float crn = sm.Gs[tkn * 64 + lane];   // next key's Gs row
        const int2 pairT2 = *(const int2*)(sm.sq + 2 * t + 6);  // t=1021 reads ybuf: unused

        // ---- register-Z row broadcast + cz (cr carried: register-immediate) ----
        const int stkn = __builtin_amdgcn_readfirstlane(tkn);
        const float e0 = rlane(Zv[0].x, stkn);      // Zv current through t-1
        const float e1 = rlane(Zv[0].y, stkn);
        const float e2 = rlane(Zv[1].x, stkn);
        const float e3 = rlane(Zv[1].y, stkn);
        const v2f E0 = { pb ? e2 : e0, pb ? e3 : e1 };   // permuted slot order
        const v2f E1 = { pb ? e0 : e2, pb ? e1 : e3 };
        const float cz = rlane(cr, stkn);           // Gs[tk*64 + tkn]

        // ---- d (fixed tree -> bitwise identical in all 4 waves; vv pre-folded) ----
        const float d = (y0 + y1) + (y2 + y3);

        // ---- p (pre-update W2) + local W2/b2 update ----
        const v2f d2 = {d, d};
        v2f p2[2];
        p2[0] = W2p[0] * d2;
        p2[1] = W2p[1] * d2;
        const float sd = GAMMA * d;
        ybias -= gma * d;
        const v2f sd2 = {sd, sd};
        W2p[0] = W2p[0] - sd2 * a2[0];
        W2p[1] = W2p[1] - sd2 * a2[1];

        // ---- cross-lane reduction + broadcast ----
        v2f dz2[2];
        reduce4(a2, p2, dz2);

        // ---- next-token state (table lag covered by cz term) ----
        const v2f cz2 = {cz, cz};
        z2[0] = E0 - cz2 * dz2[0];
        z2[1] = E1 - cz2 * dz2[1];

        // ---- prompt register-Z update (logical order) ----
        const v2f dzl0 = pb ? dz2[1] : dz2[0];
        const v2f dzl1 = pb ? dz2[0] : dz2[1];
        const v2f cr2 = {cr, cr};
        Zv[0] = Zv[0] - cr2 * dzl0;
        Zv[1] = Zv[1] - cr2 * dzl1;

        cr = crn;
        pairT = pairT1;
        pairT1 = pairT2;
    }

    // ---- peeled final step (t = 1022): key sq[2044] (carried cr row), query sq[2047] ----
    {
        const int tkn = pairT.y;                  // pairT = {sq[2046], sq[2047]}
        const v2f zero2 = {0.0f, 0.0f};
        v2f a2[2];
        a2[0] = __builtin_elementwise_max(z2[0], zero2);
        a2[1] = __builtin_elementwise_max(z2[1], zero2);
        v2f accv = a2[0] * W2p[0] + a2[1] * W2p[1];
        const float ypart = ybias + accv.x + accv.y - vv;   // vv = hs[sq[2045]] (wave0)

        sm.ybuf[0][wv][lane] = ypart;             // 1022 even -> parity 0
        __syncthreads();
        const float y0 = sm.ybuf[0][0][lane];
        const float y1 = sm.ybuf[0][1][lane];
        const float y2 = sm.ybuf[0][2][lane];
        const float y3 = sm.ybuf[0][3][lane];

        const int stkn = __builtin_amdgcn_readfirstlane(tkn);
        const float e0 = rlane(Zv[0].x, stkn);    // Zv current through step 1021
        const float e1 = rlane(Zv[0].y, stkn);
        const float e2 = rlane(Zv[1].x, stkn);
        const float e3 = rlane(Zv[1].y, stkn);
        const v2f E0 = { pb ? e2 : e0, pb ? e3 : e1 };
        const v2f E1 = { pb ? e0 : e2, pb ? e1 : e3 };
        const float cz = rlane(cr, stkn);         // carried cr = Gs[sq[2044]] row

        const float d = (y0 + y1) + (y2 + y3);

        const v2f d2 = {d, d};
        v2f p2[2];
        p2[0] = W2p[0] * d2;
        p2[1] = W2p[1] * d2;
        const float sd = GAMMA * d;
        ybias -= gma * d;
        const v2f sd2 = {sd, sd};
        W2p[0] = W2p[0] - sd2 * a2[0];
        W2p[1] = W2p[1] - sd2 * a2[1];

        v2f dz2[2];
        reduce4(a2, p2, dz2);

        const v2f cz2 = {cz, cz};
        z2[0] = E0 - cz2 * dz2[0];
        z2[1] = E1 - cz2 * dz2[1];
    }

    // ---- final eval: ctx partial per wave, combine, then out matvec ----
    {
        const v2f zero2 = {0.0f, 0.0f};
        v2f acc = __builtin_elementwise_max(z2[0], zero2) * W2p[0]
                + __builtin_elementwise_max(z2[1], zero2) * W2p[1];
        sm.ctxp[wv][lane] = ybias + acc.x + acc.y;
    }
    __syncthreads();
    if (wv0) {
        float o = outb[lane];
        for (int hh = 0; hh < 64; ++hh)
            o += (sm.ctxp[0][hh] + sm.ctxp[1][hh] + sm.ctxp[2][hh] + sm.ctxp[3][hh])
                 * outw[hh * 64 + lane];
        out[b * 64 + lane] = o;
    }
}

// ---------------- launcher ----------------
extern "C" void kernel_launch(void* const* d_in, const int* in_sizes, int n_in,
                              void* d_out, int out_size, void* d_ws, size_t ws_size,
                              hipStream_t stream) {
    const int*   seq   = (const int*)d_in[0];
    const float* embed = (const float*)d_in[1];
    const float* ffw1  = (const float*)d_in[2];
    const float* ffb1  = (const float*)d_in[3];
    const float* ffw2  = (const float*)d_in[4];
    const float* ffb2  = (const float*)d_in[5];
    const float* lng   = (const float*)d_in[6];
    const float* lnb   = (const float*)d_in[7];
    const float* w1    = (const float*)d_in[8];
    const float* b1    = (const float*)d_in[9];
    const float* w2    = (const float*)d_in[10];
    const float* b2    = (const float*)d_in[11];
    const float* outw  = (const float*)d_in[12];
    const float* outb  = (const float*)d_in[13];
    float* ws  = (float*)d_ws;
    float* out = (float*)d_out;

    hipLaunchKernelGGL(hs_kernel, dim3(64), dim3(128), 0, stream,
                       embed, ffw1, ffb1, ffw2, ffb2, lng, lnb, ws);
    hipLaunchKernelGGL(gz_kernel, dim3(64), dim3(64), 0, stream, w1, b1, ws);
    hipLaunchKernelGGL(ttt_kernel, dim3(256), dim3(256), 0, stream,
                       seq, w2, b2, outw, outb, ws, out);
}

// Round 10
// 327.290 us; speedup vs baseline: 1.6808x; 1.0992x over previous
//
#include <hip/hip_runtime.h>

#define TSTEPS 1023
#define GAMMA  (0.01f / 32.0f)   // LR * dL/dy scale: 2/(64*2) folded
#define EPSV   1e-5f

// workspace layout (float offsets)
#define WS_HS 0       // 64*64 hs table
#define WS_G  4096    // 64*64 PRE-SCALED gram: Gs = GAMMA*G + GAMMA
#define WS_Z0 8192    // 64*16 initial Ztilde = hs@w1 + b1

typedef float v2f __attribute__((ext_vector_type(2)));
typedef unsigned int v2u __attribute__((ext_vector_type(2)));

template<int CTRL>
__device__ __forceinline__ float dppmov(float x) {
    return __int_as_float(__builtin_amdgcn_update_dpp(0, __float_as_int(x), CTRL, 0xF, 0xF, true));
}
__device__ __forceinline__ v2u swap16(float a, float b) {
    return __builtin_amdgcn_permlane16_swap(__float_as_uint(a), __float_as_uint(b), false, false);
}
__device__ __forceinline__ v2u swap32(float a, float b) {
    return __builtin_amdgcn_permlane32_swap(__float_as_uint(a), __float_as_uint(b), false, false);
}
__device__ __forceinline__ float rlane(float v, int sl) {
    return __int_as_float(__builtin_amdgcn_readlane(__float_as_int(v), sl));
}
#define U2F(x) __uint_as_float(x)

// Raw barrier WITHOUT the lgkmcnt(0) drain __syncthreads emits. The LDS pipe
// services requests in arrival order: the ypart ds_write (issued pre-arrival)
// is ordered ahead of any post-release ds_read. Compile-time fences pin the
// compiler's ordering; HW waitcnts for each wave's own read results are still
// auto-inserted before use. Saves the ~100-120cy write-retire drain per step.
__device__ __forceinline__ void xbar() {
    asm volatile("" ::: "memory");
    __builtin_amdgcn_s_barrier();
    asm volatile("" ::: "memory");
}

// ---------------- kernel A: hs table (per-token embed->FFN->LN), 64 blocks ----------------
__global__ void hs_kernel(const float* __restrict__ embed,
                          const float* __restrict__ ffw1, const float* __restrict__ ffb1,
                          const float* __restrict__ ffw2, const float* __restrict__ ffb2,
                          const float* __restrict__ lng,  const float* __restrict__ lnb,
                          float* __restrict__ ws) {
    __shared__ float e[64];
    __shared__ float a1[128];
    int w = blockIdx.x;
    int tid = threadIdx.x;
    if (tid < 64) e[tid] = embed[w * 64 + tid];
    __syncthreads();
    float z1 = ffb1[tid];
    for (int x = 0; x < 64; ++x) z1 += e[x] * ffw1[x * 128 + tid];
    a1[tid] = fmaxf(z1, 0.0f);
    __syncthreads();
    if (tid < 64) {
        float f = ffb2[tid];
        for (int i = 0; i < 128; ++i) f += a1[i] * ffw2[i * 64 + tid];
        float hv = e[tid] + f;
        float s = hv;
#pragma unroll
        for (int m = 32; m >= 1; m >>= 1) s += __shfl_xor(s, m);
        float mu = s * (1.0f / 64.0f);
        float dv = hv - mu;
        float vs = dv * dv;
#pragma unroll
        for (int m = 32; m >= 1; m >>= 1) vs += __shfl_xor(vs, m);
        float rstd = 1.0f / sqrtf(vs * (1.0f / 64.0f) + EPSV);
        ws[WS_HS + w * 64 + tid] = dv * rstd * lng[tid] + lnb[tid];
    }
}

// ---------------- kernel B: pre-scaled Gram + Ztilde0, 64 blocks ----------------
__global__ void gz_kernel(const float* __restrict__ w1, const float* __restrict__ b1,
                          float* __restrict__ ws) {
    __shared__ float row[64];
    int w = blockIdx.x, tid = threadIdx.x;
    row[tid] = ws[WS_HS + w * 64 + tid];
    __syncthreads();
    float g = 0.0f;
    for (int x = 0; x < 64; ++x) g += row[x] * ws[WS_HS + tid * 64 + x];
    ws[WS_G + w * 64 + tid] = GAMMA * g + GAMMA;      // pre-scaled
    if (tid < 16) {
        float z = b1[tid];
        for (int x = 0; x < 64; ++x) z += row[x] * w1[x * 16 + tid];
        ws[WS_Z0 + w * 16 + tid] = z;
    }
}

// ---------------- main kernel: 4-wave j-split, register Z (R3 verified) + raw barrier ----------------
// R10 = byte-identical R3 structure (verified 280us kernel) with the two
// in-loop __syncthreads replaced by raw s_barrier (no lgkmcnt(0) drain).
// R9's asymmetric tweaks reverted: all waves symmetric (barrier releases on
// LAST arrival, so any per-wave extra work delays the whole step).
// Loop-LDS hazard audit: only in-loop writes are the ypart exchanges; parity
// ping-pong separates a buffer's read (step t) from its next write (t+2) by
// two barriers (~1300cy); each wave's own y-consumption has compiler waitcnts.
struct TTT4Smem {
    float hs[4096];
    float Gs[4096];
    int   sq[2048];                 // unguarded prefetch reads sq[2048..2049] -> land in ybuf (harmless)
    float ybuf[2][4][64];           // [parity][wave][lane] y-partial exchange
    float ctxp[4][64];              // final ctx partials
};

__device__ __forceinline__ void reduce4(const v2f* a2, const v2f* p2, v2f* dz2) {
    // fold lane bit0: partner lane's slot m^2 is the same logical j
    float q0 = p2[0].x + dppmov<0xB1>(p2[1].x);
    float q1 = p2[0].y + dppmov<0xB1>(p2[1].y);
    // relu mask (slot-aligned)
    float rm0 = (a2[0].x > 0.0f) ? q0 : 0.0f;
    float rm1 = (a2[0].y > 0.0f) ? q1 : 0.0f;
    // fold b4 (encodes q-index into b4) then sum over b5
    v2u f01 = swap16(rm0, rm1);
    float T = U2F(f01[0]) + U2F(f01[1]);        // j = b4 + 2*b0, summed over b4-pair
    v2u g01 = swap32(T, T);
    T = U2F(g01[0]) + U2F(g01[1]);              // summed over b5
    // orbit sums over lane bits 1,2,3
    T = T + dppmov<0x122>(T);   // row_ror:2
    T = T + dppmov<0x124>(T);   // row_ror:4
    T = T + dppmov<0x128>(T);   // row_ror:8
    // broadcast: T = dz[b4 + 2*b0] -> all 4 slots (slot m <-> j = m ^ 2*b0)
    v2u u01 = swap16(T, T);
    const float A0 = U2F(u01[0]);               // dz[0 ^ 2b0] -> slot 0
    const float A1 = U2F(u01[1]);               // dz[1 ^ 2b0] -> slot 1
    dz2[0] = {A0, A1};
    dz2[1] = {dppmov<0xB1>(A0), dppmov<0xB1>(A1)};   // slots 2,3 (other b0)
}

__launch_bounds__(256, 1)
__global__ void ttt_kernel(const int* __restrict__ seq,
                           const float* __restrict__ w2, const float* __restrict__ b2i,
                           const float* __restrict__ outw, const float* __restrict__ outb,
                           const float* __restrict__ ws, float* __restrict__ out) {
    __shared__ TTT4Smem sm;

    const int b    = blockIdx.x;
    const int tid  = threadIdx.x;
    const int wv   = tid >> 6;
    const int lane = tid & 63;
    const int b0   = lane & 1;
    const int X    = b0 << 1;              // slot xor: logical j = 4*wv + (slot ^ X)
    const bool pb  = (b0 != 0);
    const bool wv0 = (wv == 0);

    {   // vectorized staging (256 threads)
        float4*       hv = (float4*)sm.hs;
        const float4* sv = (const float4*)(ws + WS_HS);
#pragma unroll
        for (int m = 0; m < 4; ++m) hv[m * 256 + tid] = sv[m * 256 + tid];
        float4*       gv = (float4*)sm.Gs;
        const float4* gs = (const float4*)(ws + WS_G);
#pragma unroll
        for (int m = 0; m < 4; ++m) gv[m * 256 + tid] = gs[m * 256 + tid];
        int4*       qv = (int4*)sm.sq;
        const int4* qs = (const int4*)(seq + b * 2048);
#pragma unroll
        for (int m = 0; m < 2; ++m) qv[m * 256 + tid] = qs[m * 256 + tid];
    }

    // Z state: row = lane, this wave's 4 j-columns, LOGICAL order, registers only
    v2f Zv[2];
    {
        const float4 z0 = *(const float4*)(ws + WS_Z0 + lane * 16 + 4 * wv);
        Zv[0] = {z0.x, z0.y};
        Zv[1] = {z0.z, z0.w};
    }

    // W2 in permuted slot order for this wave's j-slice
    v2f W2p[2];
#pragma unroll
    for (int i = 0; i < 2; ++i) {
        v2f w;
        w.x = w2[(4 * wv + ((2 * i) ^ X)) * 64 + lane];
        w.y = w2[(4 * wv + ((2 * i + 1) ^ X)) * 64 + lane];
        W2p[i] = w;
    }
    float ybias = wv0 ? b2i[lane] : 0.0f;     // b2 lives in wave0's y-partial only
    const float gma = wv0 ? GAMMA : 0.0f;
    __syncthreads();                          // staging barrier: full drain (kept)

    // z2 init: row sq[0] broadcast from registers via readlane, permuted slots
    int tk = sm.sq[0];
    v2f z2[2];
    {
        const int stk = __builtin_amdgcn_readfirstlane(tk);
        const float e0 = rlane(Zv[0].x, stk);
        const float e1 = rlane(Zv[0].y, stk);
        const float e2 = rlane(Zv[1].x, stk);
        const float e3 = rlane(Zv[1].y, stk);
        z2[0] = { pb ? e2 : e0, pb ? e3 : e1 };
        z2[1] = { pb ? e0 : e2, pb ? e1 : e3 };
    }
    float vv = sm.hs[sm.sq[1] * 64 + lane];

    int2 pairT  = *(const int2*)(sm.sq + 2);
    int2 pairT1 = *(const int2*)(sm.sq + 4);

    // main loop: steps 0..1021 (last step peeled)
#pragma unroll 2
    for (int t = 0; t < TSTEPS - 1; ++t) {
        const int tkn = pairT.x;
        const int tvn = pairT.y;
        const int par = t & 1;

        // ---- forward on own j-slice ----
        const v2f zero2 = {0.0f, 0.0f};
        v2f a2[2];
        a2[0] = __builtin_elementwise_max(z2[0], zero2);
        a2[1] = __builtin_elementwise_max(z2[1], zero2);
        v2f accv = a2[0] * W2p[0] + a2[1] * W2p[1];
        const float ypart = ybias + accv.x + accv.y;

        // ---- y exchange (parity ping-pong, RAW barrier: no pre-drain) ----
        sm.ybuf[par][wv][lane] = ypart;
        xbar();
        const float y0 = sm.ybuf[par][0][lane];
        const float y1 = sm.ybuf[par][1][lane];
        const float y2 = sm.ybuf[par][2][lane];
        const float y3 = sm.ybuf[par][3][lane];

        // ---- off-chain: prefetch reads + register-Z row broadcast ----
        const float vnext = sm.hs[tvn * 64 + lane];
        const float cr = sm.Gs[tk * 64 + lane];     // pre-scaled gamma*(G+1), row tk
        const int2 pairT2 = *(const int2*)(sm.sq + 2 * t + 6);  // t=1021 reads ybuf: unused
        const int stkn = __builtin_amdgcn_readfirstlane(tkn);
        const float e0 = rlane(Zv[0].x, stkn);      // Zv current through t-1
        const float e1 = rlane(Zv[0].y, stkn);
        const float e2 = rlane(Zv[1].x, stkn);
        const float e3 = rlane(Zv[1].y, stkn);
        const v2f E0 = { pb ? e2 : e0, pb ? e3 : e1 };   // permuted slot order
        const v2f E1 = { pb ? e0 : e2, pb ? e1 : e3 };
        const float cz = rlane(cr, stkn);           // Gs[tk*64 + tkn]

        // ---- d (fixed tree -> bitwise identical in all 4 waves) ----
        const float d = ((y0 + y1) + (y2 + y3)) - vv;

        // ---- p (pre-update W2) + local W2/b2 update ----
        const v2f d2 = {d, d};
        v2f p2[2];
        p2[0] = W2p[0] * d2;
        p2[1] = W2p[1] * d2;
        const float sd = GAMMA * d;
        ybias -= gma * d;
        const v2f sd2 = {sd, sd};
        W2p[0] = W2p[0] - sd2 * a2[0];
        W2p[1] = W2p[1] - sd2 * a2[1];

        // ---- cross-lane reduction + broadcast ----
        v2f dz2[2];
        reduce4(a2, p2, dz2);

        // ---- next-token state (table lag covered by cz term) ----
        const v2f cz2 = {cz, cz};
        z2[0] = E0 - cz2 * dz2[0];
        z2[1] = E1 - cz2 * dz2[1];

        // ---- prompt register-Z update (logical order) ----
        const v2f dzl0 = pb ? dz2[1] : dz2[0];
        const v2f dzl1 = pb ? dz2[0] : dz2[1];
        const v2f cr2 = {cr, cr};
        Zv[0] = Zv[0] - cr2 * dzl0;
        Zv[1] = Zv[1] - cr2 * dzl1;

        vv = vnext;
        tk = tkn;
        pairT = pairT1;
        pairT1 = pairT2;
    }

    // ---- peeled final step (t = 1022): tkn = query token sq[2047] ----
    {
        const int tkn = pairT.y;                  // pairT = {sq[2046], sq[2047]}
        const v2f zero2 = {0.0f, 0.0f};
        v2f a2[2];
        a2[0] = __builtin_elementwise_max(z2[0], zero2);
        a2[1] = __builtin_elementwise_max(z2[1], zero2);
        v2f accv = a2[0] * W2p[0] + a2[1] * W2p[1];
        const float ypart = ybias + accv.x + accv.y;

        sm.ybuf[0][wv][lane] = ypart;             // 1022 even -> parity 0
        xbar();
        const float y0 = sm.ybuf[0][0][lane];
        const float y1 = sm.ybuf[0][1][lane];
        const float y2 = sm.ybuf[0][2][lane];
        const float y3 = sm.ybuf[0][3][lane];

        const float cr = sm.Gs[tk * 64 + lane];
        const int stkn = __builtin_amdgcn_readfirstlane(tkn);
        const float e0 = rlane(Zv[0].x, stkn);    // Zv current through step 1021
        const float e1 = rlane(Zv[0].y, stkn);
        const float e2 = rlane(Zv[1].x, stkn);
        const float e3 = rlane(Zv[1].y, stkn);
        const v2f E0 = { pb ? e2 : e0, pb ? e3 : e1 };
        const v2f E1 = { pb ? e0 : e2, pb ? e1 : e3 };
        const float cz = rlane(cr, stkn);

        const float d = ((y0 + y1) + (y2 + y3)) - vv;

        const v2f d2 = {d, d};
        v2f p2[2];
        p2[0] = W2p[0] * d2;
        p2[1] = W2p[1] * d2;
        const float sd = GAMMA * d;
        ybias -= gma * d;
        const v2f sd2 = {sd, sd};
        W2p[0] = W2p[0] - sd2 * a2[0];
        W2p[1] = W2p[1] - sd2 * a2[1];

        v2f dz2[2];
        reduce4(a2, p2, dz2);

        const v2f cz2 = {cz, cz};
        z2[0] = E0 - cz2 * dz2[0];
        z2[1] = E1 - cz2 * dz2[1];
    }

    // ---- final eval: ctx partial per wave, combine, then out matvec ----
    {
        const v2f zero2 = {0.0f, 0.0f};
        v2f acc = __builtin_elementwise_max(z2[0], zero2) * W2p[0]
                + __builtin_elementwise_max(z2[1], zero2) * W2p[1];
        sm.ctxp[wv][lane] = ybias + acc.x + acc.y;
    }
    __syncthreads();                              // epilogue barrier: full drain (kept)
    if (wv0) {
        float o = outb[lane];
        for (int hh = 0; hh < 64; ++hh)
            o += (sm.ctxp[0][hh] + sm.ctxp[1][hh] + sm.ctxp[2][hh] + sm.ctxp[3][hh])
                 * outw[hh * 64 + lane];
        out[b * 64 + lane] = o;
    }
}

// ---------------- launcher ----------------
extern "C" void kernel_launch(void* const* d_in, const int* in_sizes, int n_in,
                              void* d_out, int out_size, void* d_ws, size_t ws_size,
                              hipStream_t stream) {
    const int*   seq   = (const int*)d_in[0];
    const float* embed = (const float*)d_in[1];
    const float* ffw1  = (const float*)d_in[2];
    const float* ffb1  = (const float*)d_in[3];
    const float* ffw2  = (const float*)d_in[4];
    const float* ffb2  = (const float*)d_in[5];
    const float* lng   = (const float*)d_in[6];
    const float* lnb   = (const float*)d_in[7];
    const float* w1    = (const float*)d_in[8];
    const float* b1    = (const float*)d_in[9];
    const float* w2    = (const float*)d_in[10];
    const float* b2    = (const float*)d_in[11];
    const float* outw  = (const float*)d_in[12];
    const float* outb  = (const float*)d_in[13];
    float* ws  = (float*)d_ws;
    float* out = (float*)d_out;

    hipLaunchKernelGGL(hs_kernel, dim3(64), dim3(128), 0, stream,
                       embed, ffw1, ffb1, ffw2, ffb2, lng, lnb, ws);
    hipLaunchKernelGGL(gz_kernel, dim3(64), dim3(64), 0, stream, w1, b1, ws);
    hipLaunchKernelGGL(ttt_kernel, dim3(256), dim3(256), 0, stream,
                       seq, w2, b2, outw, outb, ws, out);
}